// Round 1
// baseline (299.205 us; speedup 1.0000x reference)
//
#include <hip/hip_runtime.h>

// Problem constants (hard-coded from reference: SHAPES fixed at trace time)
// L: (T,H,W) -> grid (Hg=T*H, W), start offsets 0,6144,7680,8064; LEN=8160.
// Wl = 48>>l ; Hgl = 128>>l ; start = 8192 - (8192 >> (2*l))

#define LEN 8160

// ---------------------------------------------------------------------------
// Pack Ws|Wa|Wts|Wta into one (256,768) B matrix + concat bias, so all four
// query projections run as a single GEMM.
// proj row layout per q: [0,256)=c_off  [256,384)=c_attn  [384,640)=ts_off
//                        [640,768)=t_attn
// ---------------------------------------------------------------------------
__global__ __launch_bounds__(256) void pack_kernel(
    const float* __restrict__ Ws, const float* __restrict__ bs,
    const float* __restrict__ Wa, const float* __restrict__ ba,
    const float* __restrict__ Wts, const float* __restrict__ bts,
    const float* __restrict__ Wta, const float* __restrict__ bta,
    float* __restrict__ Bcat, float* __restrict__ bcat)
{
    int idx = blockIdx.x * 256 + threadIdx.x;
    if (idx < 256 * 768) {
        int k = idx / 768, j = idx % 768;
        float v;
        if (j < 256)      v = Ws [k * 256 + j];
        else if (j < 384) v = Wa [k * 128 + (j - 256)];
        else if (j < 640) v = Wts[k * 256 + (j - 384)];
        else              v = Wta[k * 128 + (j - 640)];
        Bcat[idx] = v;
    } else if (idx < 256 * 768 + 768) {
        int j = idx - 256 * 768;
        float v;
        if (j < 256)      v = bs [j];
        else if (j < 384) v = ba [j - 256];
        else if (j < 640) v = bts[j - 384];
        else              v = bta[j - 640];
        bcat[j] = v;
    }
}

// ---------------------------------------------------------------------------
// fp32 GEMM with bias: C[M,N] = A[M,K] @ B[K,N] + bias[N]
// 64x64 block tile, BK=16, 256 threads, 4x4 micro-tile per thread.
// Requires N%64==0, K%16==0 (true here: N in {256,768}, K=256). M guarded.
// ---------------------------------------------------------------------------
__global__ __launch_bounds__(256) void gemm_bias_kernel(
    const float* __restrict__ A, const float* __restrict__ B,
    const float* __restrict__ bias, float* __restrict__ C,
    int M, int N, int K)
{
    __shared__ float As[16][64];   // transposed: As[k][m]
    __shared__ float Bs[16][64];   // Bs[k][n]
    const int tid = threadIdx.x;
    const int bx = blockIdx.x, by = blockIdx.y;
    const int tx = tid & 15, ty = tid >> 4;
    // staging assignments
    const int am = tid >> 2;              // 0..63  (A row within tile)
    const int ak = (tid & 3) << 2;        // 0,4,8,12
    const int bk = tid >> 4;              // 0..15  (B row within tile)
    const int bn = (tid & 15) << 2;       // 0..60
    const int arow = by * 64 + am;
    const float* Aptr = A + (size_t)arow * K + ak;
    const float* Bptr = B + (size_t)bk * N + bx * 64 + bn;

    float acc[4][4] = {{0.f}};
    for (int k0 = 0; k0 < K; k0 += 16) {
        float4 av = make_float4(0.f, 0.f, 0.f, 0.f);
        if (arow < M) av = *(const float4*)(Aptr + k0);
        float4 bv = *(const float4*)(Bptr + (size_t)k0 * N);
        As[ak + 0][am] = av.x; As[ak + 1][am] = av.y;
        As[ak + 2][am] = av.z; As[ak + 3][am] = av.w;
        *(float4*)(&Bs[bk][bn]) = bv;
        __syncthreads();
        #pragma unroll
        for (int kk = 0; kk < 16; kk++) {
            float a[4], b[4];
            *(float4*)a = *(const float4*)(&As[kk][ty << 2]);
            *(float4*)b = *(const float4*)(&Bs[kk][tx << 2]);
            #pragma unroll
            for (int i = 0; i < 4; i++)
                #pragma unroll
                for (int j = 0; j < 4; j++)
                    acc[i][j] = fmaf(a[i], b[j], acc[i][j]);
        }
        __syncthreads();
    }
    const int row0 = by * 64 + (ty << 2);
    const int col0 = bx * 64 + (tx << 2);
    float4 bb = *(const float4*)(bias + col0);
    #pragma unroll
    for (int i = 0; i < 4; i++) {
        int r = row0 + i;
        if (r < M) {
            float4 o;
            o.x = acc[i][0] + bb.x; o.y = acc[i][1] + bb.y;
            o.z = acc[i][2] + bb.z; o.w = acc[i][3] + bb.w;
            *(float4*)(C + (size_t)r * N + col0) = o;
        }
    }
}

// ---------------------------------------------------------------------------
// Deformable sampling. One block per query; 8 heads x 32 lanes.
// Phase 1: lane = point index (32 points = 16 current + 16 temporal across
//          4 levels). Compute location (pixel coords) + joint softmax weight,
//          stash (x, y, w, packed level meta) in LDS as float4.
// Phase 2: lane = channel d. Each 32-lane group bilinearly samples all 32
//          points; per corner the group reads 32 consecutive floats (128B).
// ---------------------------------------------------------------------------
__global__ __launch_bounds__(256) void sample_kernel(
    const float* __restrict__ value,   // (8160, 8, 32)
    const float* __restrict__ proj,    // (8160, 768)
    const float* __restrict__ refp,    // (8160, 4, 2)
    const float* __restrict__ toff,    // (8160, 4, 2, 2)
    float* __restrict__ out)           // (8160, 256) head-major channels
{
    const int q = blockIdx.x;
    const int head = threadIdx.x >> 5;
    const int lane = threadIdx.x & 31;
    __shared__ float4 s_pt[8][32];

    const float* p = proj + (size_t)q * 768;

    // ---- phase 1: locations + softmax ----
    {
        const int i = lane;
        float logit, ox, oy, rx, ry;
        int l;
        if (i < 16) {
            l = i >> 2; int pt2 = i & 3;
            logit = p[256 + head * 16 + i];
            ox = p[head * 32 + l * 8 + pt2 * 2 + 0];
            oy = p[head * 32 + l * 8 + pt2 * 2 + 1];
            rx = refp[q * 8 + l * 2 + 0];
            ry = refp[q * 8 + l * 2 + 1];
        } else {
            int j = i - 16; l = j >> 2;
            int tp = j & 3, tw = tp >> 1, nt = tp & 1;
            logit = p[640 + head * 16 + j];
            ox = p[384 + head * 32 + l * 8 + tw * 4 + nt * 2 + 0];
            oy = p[384 + head * 32 + l * 8 + tw * 4 + nt * 2 + 1];
            rx = refp[q * 8 + l * 2 + 0] + toff[q * 16 + l * 4 + tw * 2 + 0];
            ry = refp[q * 8 + l * 2 + 1] + toff[q * 16 + l * 4 + tw * 2 + 1];
        }
        const int Wl = 48 >> l;
        const int Hgl = 128 >> l;
        const int st = 8192 - (8192 >> (2 * l));
        const float fW = (float)Wl, fHg = (float)Hgl;
        // matches reference: loc = ref + off/norm ; pix = loc*dim - 0.5
        float x = (rx + ox / fW) * fW - 0.5f;
        float y = (ry + oy / fHg) * fHg - 0.5f;

        // joint softmax over the 32 logits of this (q, head)
        float m = logit;
        #pragma unroll
        for (int off = 16; off > 0; off >>= 1)
            m = fmaxf(m, __shfl_xor(m, off, 32));
        float e = expf(logit - m);
        float s = e;
        #pragma unroll
        for (int off = 16; off > 0; off >>= 1)
            s += __shfl_xor(s, off, 32);
        float w = e / s;

        unsigned meta = (unsigned)st | ((unsigned)Wl << 16) | ((unsigned)Hgl << 24);
        s_pt[head][lane] = make_float4(x, y, w, __uint_as_float(meta));
    }
    __syncthreads();

    // ---- phase 2: bilinear gather + weighted accumulate ----
    const int d = lane;
    const float* vh = value + head * 32 + d;
    float acc = 0.f;
    #pragma unroll 4
    for (int i = 0; i < 32; i++) {
        float4 pt = s_pt[head][i];
        unsigned meta = __float_as_uint(pt.w);
        int st  = (int)(meta & 0xFFFFu);
        int Wl  = (int)((meta >> 16) & 0xFFu);
        int Hgl = (int)((meta >> 24) & 0xFFu);
        float fx = floorf(pt.x), fy = floorf(pt.y);
        float wx = pt.x - fx, wy = pt.y - fy;
        int x0 = (int)fx, y0 = (int)fy;
        int x1 = x0 + 1, y1 = y0 + 1;
        float m00 = ((unsigned)x0 < (unsigned)Wl && (unsigned)y0 < (unsigned)Hgl) ? 1.f : 0.f;
        float m10 = ((unsigned)x1 < (unsigned)Wl && (unsigned)y0 < (unsigned)Hgl) ? 1.f : 0.f;
        float m01 = ((unsigned)x0 < (unsigned)Wl && (unsigned)y1 < (unsigned)Hgl) ? 1.f : 0.f;
        float m11 = ((unsigned)x1 < (unsigned)Wl && (unsigned)y1 < (unsigned)Hgl) ? 1.f : 0.f;
        int cx0 = min(max(x0, 0), Wl - 1), cx1 = min(max(x1, 0), Wl - 1);
        int cy0 = min(max(y0, 0), Hgl - 1), cy1 = min(max(y1, 0), Hgl - 1);
        const float* b = vh + st * 256;
        float v00 = b[(cy0 * Wl + cx0) * 256] * m00;
        float v10 = b[(cy0 * Wl + cx1) * 256] * m10;
        float v01 = b[(cy1 * Wl + cx0) * 256] * m01;
        float v11 = b[(cy1 * Wl + cx1) * 256] * m11;
        float sx0 = 1.f - wx, sy0 = 1.f - wy;
        acc = fmaf(pt.z, (v00 * sx0 + v10 * wx) * sy0 + (v01 * sx0 + v11 * wx) * wy, acc);
    }
    out[(size_t)q * 256 + head * 32 + d] = acc;
}

// ---------------------------------------------------------------------------
extern "C" void kernel_launch(void* const* d_in, const int* in_sizes, int n_in,
                              void* d_out, int out_size, void* d_ws, size_t ws_size,
                              hipStream_t stream)
{
    const float* query = (const float*)d_in[0];
    const float* refp  = (const float*)d_in[1];
    const float* toff  = (const float*)d_in[2];
    const float* inpf  = (const float*)d_in[3];
    // d_in[4], d_in[5]: spatial shapes / level starts (compile-time constants)
    const float* Wv  = (const float*)d_in[6];
    const float* bv  = (const float*)d_in[7];
    const float* Ws_ = (const float*)d_in[8];
    const float* bs_ = (const float*)d_in[9];
    const float* Wa  = (const float*)d_in[10];
    const float* ba  = (const float*)d_in[11];
    const float* Wts = (const float*)d_in[12];
    const float* bts = (const float*)d_in[13];
    const float* Wta = (const float*)d_in[14];
    const float* bta = (const float*)d_in[15];
    const float* Wo  = (const float*)d_in[16];
    const float* bo  = (const float*)d_in[17];
    float* out = (float*)d_out;

    float* ws      = (float*)d_ws;
    float* value   = ws;                         // 8160*256
    float* proj    = value + (size_t)LEN * 256;  // 8160*768
    float* attnout = proj + (size_t)LEN * 768;   // 8160*256
    float* Bcat    = attnout + (size_t)LEN * 256; // 256*768
    float* bcat    = Bcat + 256 * 768;           // 768

    dim3 blk(256);
    pack_kernel<<<771, blk, 0, stream>>>(Ws_, bs_, Wa, ba, Wts, bts, Wta, bta,
                                         Bcat, bcat);
    // value = input_flatten @ Wv + bv
    gemm_bias_kernel<<<dim3(4, 128), blk, 0, stream>>>(inpf, Wv, bv, value,
                                                       LEN, 256, 256);
    // proj = query @ [Ws|Wa|Wts|Wta] + bias
    gemm_bias_kernel<<<dim3(12, 128), blk, 0, stream>>>(query, Bcat, bcat, proj,
                                                        LEN, 768, 256);
    // deformable attention core
    sample_kernel<<<LEN, blk, 0, stream>>>(value, proj, refp, toff, attnout);
    // out = attnout @ Wo + bo
    gemm_bias_kernel<<<dim3(4, 128), blk, 0, stream>>>(attnout, Wo, bo, out,
                                                       LEN, 256, 256);
}

// Round 2
// 248.064 us; speedup vs baseline: 1.2062x; 1.2062x over previous
//
#include <hip/hip_runtime.h>

// Problem constants (hard-coded from reference: SHAPES fixed at trace time)
// L: (T,H,W) -> grid (Hg=T*H, W), start offsets 0,6144,7680,8064; LEN=8160.
// Wl = 48>>l ; Hgl = 128>>l ; start = 8192 - (8192 >> (2*l))

#define LEN 8160

// ---------------------------------------------------------------------------
// Pack Ws|Wa|Wts|Wta into one (256,768) B matrix + concat bias.
// proj row layout per q: [0,256)=c_off  [256,384)=c_attn  [384,640)=ts_off
//                        [640,768)=t_attn
// ---------------------------------------------------------------------------
__global__ __launch_bounds__(256) void pack_kernel(
    const float* __restrict__ Ws, const float* __restrict__ bs,
    const float* __restrict__ Wa, const float* __restrict__ ba,
    const float* __restrict__ Wts, const float* __restrict__ bts,
    const float* __restrict__ Wta, const float* __restrict__ bta,
    float* __restrict__ Bcat, float* __restrict__ bcat)
{
    int idx = blockIdx.x * 256 + threadIdx.x;
    if (idx < 256 * 768) {
        int k = idx / 768, j = idx % 768;
        float v;
        if (j < 256)      v = Ws [k * 256 + j];
        else if (j < 384) v = Wa [k * 128 + (j - 256)];
        else if (j < 640) v = Wts[k * 256 + (j - 384)];
        else              v = Wta[k * 128 + (j - 640)];
        Bcat[idx] = v;
    } else if (idx < 256 * 768 + 768) {
        int j = idx - 256 * 768;
        float v;
        if (j < 256)      v = bs [j];
        else if (j < 384) v = ba [j - 256];
        else if (j < 640) v = bts[j - 384];
        else              v = bta[j - 640];
        bcat[j] = v;
    }
}

// ---------------------------------------------------------------------------
// fp32 GEMM with bias: C[M,N] = A[M,K] @ B[K,N] + bias[N]
// 128x64 block tile, BK=16, 256 threads, 8x4 micro-tile per thread.
// Requires N%64==0, K%16==0 (N in {256,768}, K=256). M guarded.
// ---------------------------------------------------------------------------
__global__ __launch_bounds__(256) void gemm_bias_kernel(
    const float* __restrict__ A, const float* __restrict__ B,
    const float* __restrict__ bias, float* __restrict__ C,
    int M, int N, int K)
{
    __shared__ float As[16][128];  // transposed: As[k][m]
    __shared__ float Bs[16][64];   // Bs[k][n]
    const int tid = threadIdx.x;
    const int bx = blockIdx.x, by = blockIdx.y;
    const int tx = tid & 15, ty = tid >> 4;
    // staging assignments
    const int am = tid >> 1;              // 0..127 (A row within tile)
    const int ak = (tid & 1) << 3;        // 0 or 8
    const int bk = tid >> 4;              // 0..15  (B row within tile)
    const int bn = (tid & 15) << 2;       // 0..60
    const int arow = by * 128 + am;
    const float* Aptr = A + (size_t)arow * K + ak;
    const float* Bptr = B + (size_t)bk * N + bx * 64 + bn;

    float acc[8][4] = {{0.f}};
    for (int k0 = 0; k0 < K; k0 += 16) {
        float4 a0 = make_float4(0.f, 0.f, 0.f, 0.f);
        float4 a1 = make_float4(0.f, 0.f, 0.f, 0.f);
        if (arow < M) {
            a0 = *(const float4*)(Aptr + k0);
            a1 = *(const float4*)(Aptr + k0 + 4);
        }
        float4 bv = *(const float4*)(Bptr + (size_t)k0 * N);
        As[ak + 0][am] = a0.x; As[ak + 1][am] = a0.y;
        As[ak + 2][am] = a0.z; As[ak + 3][am] = a0.w;
        As[ak + 4][am] = a1.x; As[ak + 5][am] = a1.y;
        As[ak + 6][am] = a1.z; As[ak + 7][am] = a1.w;
        *(float4*)(&Bs[bk][bn]) = bv;
        __syncthreads();
        #pragma unroll
        for (int kk = 0; kk < 16; kk++) {
            float a[8], b[4];
            *(float4*)(&a[0]) = *(const float4*)(&As[kk][ty << 3]);
            *(float4*)(&a[4]) = *(const float4*)(&As[kk][(ty << 3) + 4]);
            *(float4*)(&b[0]) = *(const float4*)(&Bs[kk][tx << 2]);
            #pragma unroll
            for (int i = 0; i < 8; i++)
                #pragma unroll
                for (int j = 0; j < 4; j++)
                    acc[i][j] = fmaf(a[i], b[j], acc[i][j]);
        }
        __syncthreads();
    }
    const int row0 = by * 128 + (ty << 3);
    const int col0 = bx * 64 + (tx << 2);
    float4 bb = *(const float4*)(bias + col0);
    #pragma unroll
    for (int i = 0; i < 8; i++) {
        int r = row0 + i;
        if (r < M) {
            float4 o;
            o.x = acc[i][0] + bb.x; o.y = acc[i][1] + bb.y;
            o.z = acc[i][2] + bb.z; o.w = acc[i][3] + bb.w;
            *(float4*)(C + (size_t)r * N + col0) = o;
        }
    }
}

// ---------------------------------------------------------------------------
// Deformable sampling. One block per query; 8 heads x 32 lanes.
// Phase 1: lane = point index. Compute location, joint softmax weight, then
//          the FULL bilinear setup: 4 clamped flat element indices + 4
//          mask-fused (attn*coef) weights -> LDS (int4 + float4 per point).
// Phase 2: lane = channel d. Per point: 2 broadcast LDS reads, 4 coalesced
//          128B-per-group gathers, 4 FMAs.
// ---------------------------------------------------------------------------
__global__ __launch_bounds__(256) void sample_kernel(
    const float* __restrict__ value,   // (8160, 8, 32)
    const float* __restrict__ proj,    // (8160, 768)
    const float* __restrict__ refp,    // (8160, 4, 2)
    const float* __restrict__ toff,    // (8160, 4, 2, 2)
    float* __restrict__ out)           // (8160, 256) head-major channels
{
    const int q = blockIdx.x;
    const int head = threadIdx.x >> 5;
    const int lane = threadIdx.x & 31;
    __shared__ int4   s_idx[8][32];
    __shared__ float4 s_w[8][32];

    const float* p = proj + (size_t)q * 768;

    // ---- phase 1: locations + softmax + bilinear setup ----
    {
        const int i = lane;
        float logit, ox, oy, rx, ry;
        int l;
        if (i < 16) {
            l = i >> 2; int pt2 = i & 3;
            logit = p[256 + head * 16 + i];
            ox = p[head * 32 + l * 8 + pt2 * 2 + 0];
            oy = p[head * 32 + l * 8 + pt2 * 2 + 1];
            rx = refp[q * 8 + l * 2 + 0];
            ry = refp[q * 8 + l * 2 + 1];
        } else {
            int j = i - 16; l = j >> 2;
            int tp = j & 3, tw = tp >> 1, nt = tp & 1;
            logit = p[640 + head * 16 + j];
            ox = p[384 + head * 32 + l * 8 + tw * 4 + nt * 2 + 0];
            oy = p[384 + head * 32 + l * 8 + tw * 4 + nt * 2 + 1];
            rx = refp[q * 8 + l * 2 + 0] + toff[q * 16 + l * 4 + tw * 2 + 0];
            ry = refp[q * 8 + l * 2 + 1] + toff[q * 16 + l * 4 + tw * 2 + 1];
        }
        const int Wl = 48 >> l;
        const int Hgl = 128 >> l;
        const int st = 8192 - (8192 >> (2 * l));
        const float fW = (float)Wl, fHg = (float)Hgl;
        // matches reference: loc = ref + off/norm ; pix = loc*dim - 0.5
        float x = (rx + ox / fW) * fW - 0.5f;
        float y = (ry + oy / fHg) * fHg - 0.5f;

        // joint softmax over the 32 logits of this (q, head)
        float m = logit;
        #pragma unroll
        for (int off = 16; off > 0; off >>= 1)
            m = fmaxf(m, __shfl_xor(m, off, 32));
        float e = expf(logit - m);
        float s = e;
        #pragma unroll
        for (int off = 16; off > 0; off >>= 1)
            s += __shfl_xor(s, off, 32);
        float w = e / s;

        // bilinear setup
        float fx = floorf(x), fy = floorf(y);
        float wx = x - fx, wy = y - fy;
        int x0 = (int)fx, y0 = (int)fy;
        int x1 = x0 + 1, y1 = y0 + 1;
        float m00 = ((unsigned)x0 < (unsigned)Wl && (unsigned)y0 < (unsigned)Hgl) ? 1.f : 0.f;
        float m10 = ((unsigned)x1 < (unsigned)Wl && (unsigned)y0 < (unsigned)Hgl) ? 1.f : 0.f;
        float m01 = ((unsigned)x0 < (unsigned)Wl && (unsigned)y1 < (unsigned)Hgl) ? 1.f : 0.f;
        float m11 = ((unsigned)x1 < (unsigned)Wl && (unsigned)y1 < (unsigned)Hgl) ? 1.f : 0.f;
        int cx0 = min(max(x0, 0), Wl - 1), cx1 = min(max(x1, 0), Wl - 1);
        int cy0 = min(max(y0, 0), Hgl - 1), cy1 = min(max(y1, 0), Hgl - 1);
        int4 ii;
        ii.x = (st + cy0 * Wl + cx0) * 256;
        ii.y = (st + cy0 * Wl + cx1) * 256;
        ii.z = (st + cy1 * Wl + cx0) * 256;
        ii.w = (st + cy1 * Wl + cx1) * 256;
        float sx0 = 1.f - wx, sy0 = 1.f - wy;
        float4 ww;
        ww.x = w * sx0 * sy0 * m00;
        ww.y = w * wx  * sy0 * m10;
        ww.z = w * sx0 * wy  * m01;
        ww.w = w * wx  * wy  * m11;
        s_idx[head][lane] = ii;
        s_w[head][lane] = ww;
    }
    __syncthreads();

    // ---- phase 2: weighted gather ----
    const float* vh = value + head * 32 + lane;
    float acc = 0.f;
    #pragma unroll 4
    for (int i = 0; i < 32; i++) {
        int4 ii = s_idx[head][i];
        float4 ww = s_w[head][i];
        acc = fmaf(ww.x, vh[ii.x], acc);
        acc = fmaf(ww.y, vh[ii.y], acc);
        acc = fmaf(ww.z, vh[ii.z], acc);
        acc = fmaf(ww.w, vh[ii.w], acc);
    }
    out[(size_t)q * 256 + head * 32 + lane] = acc;
}

// ---------------------------------------------------------------------------
extern "C" void kernel_launch(void* const* d_in, const int* in_sizes, int n_in,
                              void* d_out, int out_size, void* d_ws, size_t ws_size,
                              hipStream_t stream)
{
    const float* query = (const float*)d_in[0];
    const float* refp  = (const float*)d_in[1];
    const float* toff  = (const float*)d_in[2];
    const float* inpf  = (const float*)d_in[3];
    // d_in[4], d_in[5]: spatial shapes / level starts (compile-time constants)
    const float* Wv  = (const float*)d_in[6];
    const float* bv  = (const float*)d_in[7];
    const float* Ws_ = (const float*)d_in[8];
    const float* bs_ = (const float*)d_in[9];
    const float* Wa  = (const float*)d_in[10];
    const float* ba  = (const float*)d_in[11];
    const float* Wts = (const float*)d_in[12];
    const float* bts = (const float*)d_in[13];
    const float* Wta = (const float*)d_in[14];
    const float* bta = (const float*)d_in[15];
    const float* Wo  = (const float*)d_in[16];
    const float* bo  = (const float*)d_in[17];
    float* out = (float*)d_out;

    float* ws      = (float*)d_ws;
    float* value   = ws;                          // 8160*256
    float* proj    = value + (size_t)LEN * 256;   // 8160*768
    float* attnout = proj + (size_t)LEN * 768;    // 8160*256
    float* Bcat    = attnout + (size_t)LEN * 256; // 256*768
    float* bcat    = Bcat + 256 * 768;            // 768

    dim3 blk(256);
    pack_kernel<<<771, blk, 0, stream>>>(Ws_, bs_, Wa, ba, Wts, bts, Wta, bta,
                                         Bcat, bcat);
    // value = input_flatten @ Wv + bv   (grid: N/64 x ceil(M/128))
    gemm_bias_kernel<<<dim3(4, 64), blk, 0, stream>>>(inpf, Wv, bv, value,
                                                      LEN, 256, 256);
    // proj = query @ [Ws|Wa|Wts|Wta] + bias
    gemm_bias_kernel<<<dim3(12, 64), blk, 0, stream>>>(query, Bcat, bcat, proj,
                                                       LEN, 768, 256);
    // deformable attention core
    sample_kernel<<<LEN, blk, 0, stream>>>(value, proj, refp, toff, attnout);
    // out = attnout @ Wo + bo
    gemm_bias_kernel<<<dim3(4, 64), blk, 0, stream>>>(attnout, Wo, bo, out,
                                                      LEN, 256, 256);
}

// Round 3
// 196.521 us; speedup vs baseline: 1.5225x; 1.2623x over previous
//
#include <hip/hip_runtime.h>

// Problem constants (hard-coded from reference: SHAPES fixed at trace time)
// Level l: W=48>>l, Hgrid=128>>l, start = 8192 - (8192 >> (2*l)); LEN=8160.

#define LEN 8160

typedef __attribute__((ext_vector_type(8))) short bf16x8;
typedef __attribute__((ext_vector_type(4))) float f32x4;

// Round-to-nearest-even split of fp32 into hi+lo bf16 (bf16x3 GEMM trick).
__device__ __forceinline__ void split_bf16(float v, unsigned short* hi, unsigned short* lo)
{
    unsigned u = __float_as_uint(v);
    unsigned r = (u + 0x7FFFu + ((u >> 16) & 1u)) & 0xFFFF0000u;
    float hif = __uint_as_float(r);
    float lof = v - hif;
    unsigned ul = __float_as_uint(lof);
    unsigned rl = (ul + 0x7FFFu + ((ul >> 16) & 1u)) >> 16;
    *hi = (unsigned short)(r >> 16);
    *lo = (unsigned short)rl;
}

// ---------------------------------------------------------------------------
// Pack ALL weights transposed (B^T[n][k], k contiguous = MFMA B-frag layout)
// into hi/lo bf16 planes. Row space: [0,256)=WvT  [256,1024)=BcatT(Ws|Wa|Wts|Wta)
// [1024,1280)=WoT. Also build concat bias (768) for the proj GEMM.
// ---------------------------------------------------------------------------
__global__ __launch_bounds__(256) void pack_kernel(
    const float* __restrict__ Ws, const float* __restrict__ bs,
    const float* __restrict__ Wa, const float* __restrict__ ba,
    const float* __restrict__ Wts, const float* __restrict__ bts,
    const float* __restrict__ Wta, const float* __restrict__ bta,
    const float* __restrict__ Wv, const float* __restrict__ Wo,
    unsigned short* __restrict__ Whi, unsigned short* __restrict__ Wlo,
    float* __restrict__ bcat)
{
    int idx = blockIdx.x * 256 + threadIdx.x;
    if (idx < 1280 * 256) {
        int n = idx >> 8, k = idx & 255;
        float v;
        if (n < 256) v = Wv[k * 256 + n];
        else if (n < 1024) {
            int j = n - 256;
            if (j < 256)      v = Ws [k * 256 + j];
            else if (j < 384) v = Wa [k * 128 + (j - 256)];
            else if (j < 640) v = Wts[k * 256 + (j - 384)];
            else              v = Wta[k * 128 + (j - 640)];
        } else v = Wo[k * 256 + (n - 1024)];
        unsigned short h, l; split_bf16(v, &h, &l);
        Whi[idx] = h; Wlo[idx] = l;
    } else if (idx < 1280 * 256 + 768) {
        int j = idx - 1280 * 256;
        float v;
        if (j < 256)      v = bs[j];
        else if (j < 384) v = ba[j - 256];
        else if (j < 640) v = bts[j - 384];
        else              v = bta[j - 640];
        bcat[j] = v;
    }
}

// ---------------------------------------------------------------------------
// Split fp32 A matrices (input_flatten, query) into hi/lo bf16 planes.
// Planes are allocated with 8192 rows; rows >= 8160 stay poison (0xAAAA bf16
// = tiny denormal-ish value, harmless: GEMM reads them but never stores).
// ---------------------------------------------------------------------------
__global__ __launch_bounds__(256) void convA_kernel(
    const float* __restrict__ inpf, const float* __restrict__ query,
    unsigned short* __restrict__ Ahi, unsigned short* __restrict__ Alo,
    unsigned short* __restrict__ Qhi, unsigned short* __restrict__ Qlo)
{
    int idx = blockIdx.x * 256 + threadIdx.x;   // [0, 2*LEN*256)
    int which = (idx >= LEN * 256) ? 1 : 0;
    int off = idx - which * (LEN * 256);
    float v = which ? query[off] : inpf[off];
    unsigned short h, l; split_bf16(v, &h, &l);
    if (which) { Qhi[off] = h; Qlo[off] = l; }
    else       { Ahi[off] = h; Alo[off] = l; }
}

// ---------------------------------------------------------------------------
// bf16x3 MFMA GEMM: C[M,N] = A @ B + bias, fp32-accurate.
// A given as hi/lo bf16 planes [>=8192][256] row-major (k contiguous).
// B given as transposed hi/lo planes Bt[n][256].
// Block: 256 thr = 4 waves; tile 64(M)x64(N); wave w owns rows 16w..16w+15.
// K-loop: 4 chunks of 64 k staged in LDS (B only), 2 k-tiles of 32 per chunk.
// Per k-tile per wave: 2 global A-frag loads, 8 LDS B-frag loads, 12 MFMAs.
// ---------------------------------------------------------------------------
__global__ __launch_bounds__(256) void gemm_mfma_kernel(
    const unsigned short* __restrict__ Ahi, const unsigned short* __restrict__ Alo,
    const unsigned short* __restrict__ Bhi, const unsigned short* __restrict__ Blo,
    const float* __restrict__ bias, float* __restrict__ C, int M, int N)
{
    __shared__ unsigned short BsH[64][72];   // +8 pad breaks bank aliasing
    __shared__ unsigned short BsL[64][72];
    const int tid = threadIdx.x;
    const int wave = tid >> 6, lane = tid & 63;
    const int bx = blockIdx.x, by = blockIdx.y;
    const int lm = lane & 15;     // m within 16-tile / C column
    const int kq = lane >> 4;     // k-quad (0..3)

    const int m = by * 64 + wave * 16 + lm;
    const unsigned short* aHp = Ahi + (size_t)m * 256 + kq * 8;
    const unsigned short* aLp = Alo + (size_t)m * 256 + kq * 8;

    // staging: thread t loads 16 k of row n for both planes
    const int sn = tid >> 2;
    const int sk = (tid & 3) * 16;
    const unsigned short* bHs = Bhi + (size_t)(bx * 64 + sn) * 256 + sk;
    const unsigned short* bLs = Blo + (size_t)(bx * 64 + sn) * 256 + sk;

    f32x4 acc[4] = {};
    for (int kc = 0; kc < 4; kc++) {
        *(uint4*)(&BsH[sn][sk])     = *(const uint4*)(bHs + kc * 64);
        *(uint4*)(&BsH[sn][sk + 8]) = *(const uint4*)(bHs + kc * 64 + 8);
        *(uint4*)(&BsL[sn][sk])     = *(const uint4*)(bLs + kc * 64);
        *(uint4*)(&BsL[sn][sk + 8]) = *(const uint4*)(bLs + kc * 64 + 8);
        __syncthreads();
        #pragma unroll
        for (int kt = 0; kt < 2; kt++) {
            const int ko = kc * 64 + kt * 32;
            bf16x8 ah = *(const bf16x8*)(aHp + ko);
            bf16x8 al = *(const bf16x8*)(aLp + ko);
            #pragma unroll
            for (int nt = 0; nt < 4; nt++) {
                bf16x8 bh = *(const bf16x8*)(&BsH[nt * 16 + lm][kt * 32 + kq * 8]);
                bf16x8 bl = *(const bf16x8*)(&BsL[nt * 16 + lm][kt * 32 + kq * 8]);
                acc[nt] = __builtin_amdgcn_mfma_f32_16x16x32_bf16(ah, bh, acc[nt], 0, 0, 0);
                acc[nt] = __builtin_amdgcn_mfma_f32_16x16x32_bf16(ah, bl, acc[nt], 0, 0, 0);
                acc[nt] = __builtin_amdgcn_mfma_f32_16x16x32_bf16(al, bh, acc[nt], 0, 0, 0);
            }
        }
        __syncthreads();
    }
    // C/D layout (verified m89/m91): col = lane&15, row = (lane>>4)*4 + reg
    const int row0 = by * 64 + wave * 16 + kq * 4;
    const int col = bx * 64 + lm;
    #pragma unroll
    for (int nt = 0; nt < 4; nt++) {
        float bb = bias[col + nt * 16];
        #pragma unroll
        for (int r = 0; r < 4; r++) {
            int row = row0 + r;
            if (row < M)
                C[(size_t)row * N + col + nt * 16] = acc[nt][r] + bb;
        }
    }
}

// ---------------------------------------------------------------------------
// Deformable sampling. One block per query; 8 heads x 32 lanes.
// Phase 1: lane = point. Location + joint softmax + full bilinear setup
//          (4 clamped indices, 4 mask*attn-fused weights) -> LDS.
// Phase 2: lane = channel. 2 broadcast LDS reads + 4 gathers + 4 FMA / point.
// Epilogue: write result as hi/lo bf16 planes (A operand of the out-GEMM).
// ---------------------------------------------------------------------------
__global__ __launch_bounds__(256) void sample_kernel(
    const float* __restrict__ value,   // (8160, 8, 32) fp32
    const float* __restrict__ proj,    // (8160, 768)
    const float* __restrict__ refp,    // (8160, 4, 2)
    const float* __restrict__ toff,    // (8160, 4, 2, 2)
    unsigned short* __restrict__ attn_hi,  // (8192, 256) bf16 plane
    unsigned short* __restrict__ attn_lo)
{
    const int q = blockIdx.x;
    const int head = threadIdx.x >> 5;
    const int lane = threadIdx.x & 31;
    __shared__ int4   s_idx[8][32];
    __shared__ float4 s_w[8][32];

    const float* p = proj + (size_t)q * 768;

    // ---- phase 1 ----
    {
        const int i = lane;
        float logit, ox, oy, rx, ry;
        int l;
        if (i < 16) {
            l = i >> 2; int pt2 = i & 3;
            logit = p[256 + head * 16 + i];
            ox = p[head * 32 + l * 8 + pt2 * 2 + 0];
            oy = p[head * 32 + l * 8 + pt2 * 2 + 1];
            rx = refp[q * 8 + l * 2 + 0];
            ry = refp[q * 8 + l * 2 + 1];
        } else {
            int j = i - 16; l = j >> 2;
            int tp = j & 3, tw = tp >> 1, nt = tp & 1;
            logit = p[640 + head * 16 + j];
            ox = p[384 + head * 32 + l * 8 + tw * 4 + nt * 2 + 0];
            oy = p[384 + head * 32 + l * 8 + tw * 4 + nt * 2 + 1];
            rx = refp[q * 8 + l * 2 + 0] + toff[q * 16 + l * 4 + tw * 2 + 0];
            ry = refp[q * 8 + l * 2 + 1] + toff[q * 16 + l * 4 + tw * 2 + 1];
        }
        const int Wl = 48 >> l;
        const int Hgl = 128 >> l;
        const int st = 8192 - (8192 >> (2 * l));
        const float fW = (float)Wl, fHg = (float)Hgl;
        float x = (rx + ox / fW) * fW - 0.5f;
        float y = (ry + oy / fHg) * fHg - 0.5f;

        float mx = logit;
        #pragma unroll
        for (int off = 16; off > 0; off >>= 1)
            mx = fmaxf(mx, __shfl_xor(mx, off, 32));
        float e = expf(logit - mx);
        float s = e;
        #pragma unroll
        for (int off = 16; off > 0; off >>= 1)
            s += __shfl_xor(s, off, 32);
        float w = e / s;

        float fx = floorf(x), fy = floorf(y);
        float wx = x - fx, wy = y - fy;
        int x0 = (int)fx, y0 = (int)fy;
        int x1 = x0 + 1, y1 = y0 + 1;
        float m00 = ((unsigned)x0 < (unsigned)Wl && (unsigned)y0 < (unsigned)Hgl) ? 1.f : 0.f;
        float m10 = ((unsigned)x1 < (unsigned)Wl && (unsigned)y0 < (unsigned)Hgl) ? 1.f : 0.f;
        float m01 = ((unsigned)x0 < (unsigned)Wl && (unsigned)y1 < (unsigned)Hgl) ? 1.f : 0.f;
        float m11 = ((unsigned)x1 < (unsigned)Wl && (unsigned)y1 < (unsigned)Hgl) ? 1.f : 0.f;
        int cx0 = min(max(x0, 0), Wl - 1), cx1 = min(max(x1, 0), Wl - 1);
        int cy0 = min(max(y0, 0), Hgl - 1), cy1 = min(max(y1, 0), Hgl - 1);
        int4 ii;
        ii.x = (st + cy0 * Wl + cx0) * 256;
        ii.y = (st + cy0 * Wl + cx1) * 256;
        ii.z = (st + cy1 * Wl + cx0) * 256;
        ii.w = (st + cy1 * Wl + cx1) * 256;
        float sx0 = 1.f - wx, sy0 = 1.f - wy;
        float4 ww;
        ww.x = w * sx0 * sy0 * m00;
        ww.y = w * wx  * sy0 * m10;
        ww.z = w * sx0 * wy  * m01;
        ww.w = w * wx  * wy  * m11;
        s_idx[head][lane] = ii;
        s_w[head][lane] = ww;
    }
    __syncthreads();

    // ---- phase 2 ----
    const float* vh = value + head * 32 + lane;
    float acc = 0.f;
    #pragma unroll 4
    for (int i = 0; i < 32; i++) {
        int4 ii = s_idx[head][i];
        float4 ww = s_w[head][i];
        acc = fmaf(ww.x, vh[ii.x], acc);
        acc = fmaf(ww.y, vh[ii.y], acc);
        acc = fmaf(ww.z, vh[ii.z], acc);
        acc = fmaf(ww.w, vh[ii.w], acc);
    }
    unsigned short h, l; split_bf16(acc, &h, &l);
    size_t o = (size_t)q * 256 + head * 32 + lane;
    attn_hi[o] = h;
    attn_lo[o] = l;
}

// ---------------------------------------------------------------------------
extern "C" void kernel_launch(void* const* d_in, const int* in_sizes, int n_in,
                              void* d_out, int out_size, void* d_ws, size_t ws_size,
                              hipStream_t stream)
{
    const float* query = (const float*)d_in[0];
    const float* refp  = (const float*)d_in[1];
    const float* toff  = (const float*)d_in[2];
    const float* inpf  = (const float*)d_in[3];
    const float* Wv  = (const float*)d_in[6];
    const float* bv  = (const float*)d_in[7];
    const float* Ws_ = (const float*)d_in[8];
    const float* bs_ = (const float*)d_in[9];
    const float* Wa  = (const float*)d_in[10];
    const float* ba  = (const float*)d_in[11];
    const float* Wts = (const float*)d_in[12];
    const float* bts = (const float*)d_in[13];
    const float* Wta = (const float*)d_in[14];
    const float* bta = (const float*)d_in[15];
    const float* Wo  = (const float*)d_in[16];
    const float* bo  = (const float*)d_in[17];
    float* out = (float*)d_out;

    // workspace layout (~51.5 MB)
    float* ws    = (float*)d_ws;
    float* value = ws;                              // 8160*256 f32
    float* proj  = value + (size_t)LEN * 256;       // 8160*768 f32
    float* bcat  = proj + (size_t)LEN * 768;        // 768 f32
    unsigned short* Whi = (unsigned short*)(bcat + 768);   // 1280*256 bf16
    unsigned short* Wlo = Whi + 1280 * 256;
    unsigned short* Ahi = Wlo + 1280 * 256;         // 8192*256: inpf planes, later attn planes (alias OK: stream-serial)
    unsigned short* Alo = Ahi + 8192 * 256;
    unsigned short* Qhi = Alo + 8192 * 256;         // 8192*256: query planes
    unsigned short* Qlo = Qhi + 8192 * 256;

    dim3 blk(256);
    pack_kernel<<<1284, blk, 0, stream>>>(Ws_, bs_, Wa, ba, Wts, bts, Wta, bta,
                                          Wv, Wo, Whi, Wlo, bcat);
    convA_kernel<<<2 * LEN, blk, 0, stream>>>(inpf, query, Ahi, Alo, Qhi, Qlo);
    // value = input_flatten @ Wv + bv
    gemm_mfma_kernel<<<dim3(4, 128), blk, 0, stream>>>(Ahi, Alo, Whi, Wlo,
                                                       bv, value, LEN, 256);
    // proj = query @ [Ws|Wa|Wts|Wta] + bias
    gemm_mfma_kernel<<<dim3(12, 128), blk, 0, stream>>>(Qhi, Qlo,
                                                        Whi + 256 * 256, Wlo + 256 * 256,
                                                        bcat, proj, LEN, 768);
    // deformable attention core -> attn planes (reuse Ahi/Alo: inpf planes dead)
    sample_kernel<<<LEN, blk, 0, stream>>>(value, proj, refp, toff, Ahi, Alo);
    // out = attn @ Wo + bo
    gemm_mfma_kernel<<<dim3(4, 128), blk, 0, stream>>>(Ahi, Alo,
                                                       Whi + 1024 * 256, Wlo + 1024 * 256,
                                                       bo, out, LEN, 256);
}

// Round 4
// 188.018 us; speedup vs baseline: 1.5914x; 1.0452x over previous
//
#include <hip/hip_runtime.h>

// Problem constants (hard-coded from reference: SHAPES fixed at trace time)
// Level l: W=48>>l, Hgrid=128>>l, start = 8192 - (8192 >> (2*l)); LEN=8160.

#define LEN 8160
#define NCONV (2 * LEN * 256)      // 4,177,920 convA elements
#define NPACK (1280 * 256)         // 327,680 packed weight elements

typedef __attribute__((ext_vector_type(8))) short bf16x8;
typedef __attribute__((ext_vector_type(4))) float f32x4;

// Round-to-nearest-even split of fp32 into hi+lo bf16 (bf16x3 GEMM trick).
__device__ __forceinline__ void split_bf16(float v, unsigned short* hi, unsigned short* lo)
{
    unsigned u = __float_as_uint(v);
    unsigned r = (u + 0x7FFFu + ((u >> 16) & 1u)) & 0xFFFF0000u;
    float hif = __uint_as_float(r);
    float lof = v - hif;
    unsigned ul = __float_as_uint(lof);
    unsigned rl = (ul + 0x7FFFu + ((ul >> 16) & 1u)) >> 16;
    *hi = (unsigned short)(r >> 16);
    *lo = (unsigned short)rl;
}

// ---------------------------------------------------------------------------
// prep = convA (split inpf+query into hi/lo bf16 planes) + pack (all weights
// transposed into hi/lo planes; rows [0,256)=WvT [256,1024)=BcatT [1024,1280)
// =WoT) + concat bias. One dispatch, flat index ranges.
// ---------------------------------------------------------------------------
__global__ __launch_bounds__(256) void prep_kernel(
    const float* __restrict__ inpf, const float* __restrict__ query,
    const float* __restrict__ Ws, const float* __restrict__ bs,
    const float* __restrict__ Wa, const float* __restrict__ ba,
    const float* __restrict__ Wts, const float* __restrict__ bts,
    const float* __restrict__ Wta, const float* __restrict__ bta,
    const float* __restrict__ Wv, const float* __restrict__ Wo,
    unsigned short* __restrict__ Ahi, unsigned short* __restrict__ Alo,
    unsigned short* __restrict__ Qhi, unsigned short* __restrict__ Qlo,
    unsigned short* __restrict__ Whi, unsigned short* __restrict__ Wlo,
    float* __restrict__ bcat)
{
    int idx = blockIdx.x * 256 + threadIdx.x;
    if (idx < NCONV) {
        int which = (idx >= LEN * 256) ? 1 : 0;
        int off = idx - which * (LEN * 256);
        float v = which ? query[off] : inpf[off];
        unsigned short h, l; split_bf16(v, &h, &l);
        if (which) { Qhi[off] = h; Qlo[off] = l; }
        else       { Ahi[off] = h; Alo[off] = l; }
    } else if (idx < NCONV + NPACK) {
        int j2 = idx - NCONV;
        int n = j2 >> 8, k = j2 & 255;
        float v;
        if (n < 256) v = Wv[k * 256 + n];
        else if (n < 1024) {
            int j = n - 256;
            if (j < 256)      v = Ws [k * 256 + j];
            else if (j < 384) v = Wa [k * 128 + (j - 256)];
            else if (j < 640) v = Wts[k * 256 + (j - 384)];
            else              v = Wta[k * 128 + (j - 640)];
        } else v = Wo[k * 256 + (n - 1024)];
        unsigned short h, l; split_bf16(v, &h, &l);
        Whi[j2] = h; Wlo[j2] = l;
    } else if (idx < NCONV + NPACK + 768) {
        int j = idx - (NCONV + NPACK);
        float v;
        if (j < 256)      v = bs[j];
        else if (j < 384) v = ba[j - 256];
        else if (j < 640) v = bts[j - 384];
        else              v = bta[j - 640];
        bcat[j] = v;
    }
}

// ---------------------------------------------------------------------------
// bf16x3 MFMA GEMM, dual problem-set per dispatch (block-uniform select on
// bx). C[M,N] = A @ B^T + bias. A: hi/lo planes [8192][256]; B: transposed
// hi/lo planes Bt[n][256]. Block 256 thr = 4 waves, tile 64(M)x64(N), wave
// owns 16 rows; 4 k-chunks of 64 staged in LDS (B only).
// ---------------------------------------------------------------------------
__global__ __launch_bounds__(256) void gemm_mfma_dual(
    const unsigned short* __restrict__ A0hi, const unsigned short* __restrict__ A0lo,
    const unsigned short* __restrict__ B0hi, const unsigned short* __restrict__ B0lo,
    const float* __restrict__ bias0, float* __restrict__ C0, int N0, int nbx0,
    const unsigned short* __restrict__ A1hi, const unsigned short* __restrict__ A1lo,
    const unsigned short* __restrict__ B1hi, const unsigned short* __restrict__ B1lo,
    const float* __restrict__ bias1, float* __restrict__ C1, int N1)
{
    __shared__ unsigned short BsH[64][72];   // +8 pad breaks bank aliasing
    __shared__ unsigned short BsL[64][72];
    const int tid = threadIdx.x;
    const int wave = tid >> 6, lane = tid & 63;
    int bx = blockIdx.x;
    const int by = blockIdx.y;

    const unsigned short *Ahi, *Alo, *Bhi, *Blo;
    const float* bias; float* C; int N;
    if (bx < nbx0) {
        Ahi = A0hi; Alo = A0lo; Bhi = B0hi; Blo = B0lo;
        bias = bias0; C = C0; N = N0;
    } else {
        bx -= nbx0;
        Ahi = A1hi; Alo = A1lo; Bhi = B1hi; Blo = B1lo;
        bias = bias1; C = C1; N = N1;
    }

    const int lm = lane & 15;     // m within 16-tile / C column
    const int kq = lane >> 4;     // k-quad (0..3)

    const int m = by * 64 + wave * 16 + lm;
    const unsigned short* aHp = Ahi + (size_t)m * 256 + kq * 8;
    const unsigned short* aLp = Alo + (size_t)m * 256 + kq * 8;

    const int sn = tid >> 2;
    const int sk = (tid & 3) * 16;
    const unsigned short* bHs = Bhi + (size_t)(bx * 64 + sn) * 256 + sk;
    const unsigned short* bLs = Blo + (size_t)(bx * 64 + sn) * 256 + sk;

    f32x4 acc[4] = {};
    for (int kc = 0; kc < 4; kc++) {
        *(uint4*)(&BsH[sn][sk])     = *(const uint4*)(bHs + kc * 64);
        *(uint4*)(&BsH[sn][sk + 8]) = *(const uint4*)(bHs + kc * 64 + 8);
        *(uint4*)(&BsL[sn][sk])     = *(const uint4*)(bLs + kc * 64);
        *(uint4*)(&BsL[sn][sk + 8]) = *(const uint4*)(bLs + kc * 64 + 8);
        __syncthreads();
        #pragma unroll
        for (int kt = 0; kt < 2; kt++) {
            const int ko = kc * 64 + kt * 32;
            bf16x8 ah = *(const bf16x8*)(aHp + ko);
            bf16x8 al = *(const bf16x8*)(aLp + ko);
            #pragma unroll
            for (int nt = 0; nt < 4; nt++) {
                bf16x8 bh = *(const bf16x8*)(&BsH[nt * 16 + lm][kt * 32 + kq * 8]);
                bf16x8 bl = *(const bf16x8*)(&BsL[nt * 16 + lm][kt * 32 + kq * 8]);
                acc[nt] = __builtin_amdgcn_mfma_f32_16x16x32_bf16(ah, bh, acc[nt], 0, 0, 0);
                acc[nt] = __builtin_amdgcn_mfma_f32_16x16x32_bf16(ah, bl, acc[nt], 0, 0, 0);
                acc[nt] = __builtin_amdgcn_mfma_f32_16x16x32_bf16(al, bh, acc[nt], 0, 0, 0);
            }
        }
        __syncthreads();
    }
    // C/D layout (verified m89/m91): col = lane&15, row = (lane>>4)*4 + reg
    const int row0 = by * 64 + wave * 16 + kq * 4;
    const int col = bx * 64 + lm;
    #pragma unroll
    for (int nt = 0; nt < 4; nt++) {
        float bb = bias[col + nt * 16];
        #pragma unroll
        for (int r = 0; r < 4; r++) {
            int row = row0 + r;
            if (row < LEN)
                C[(size_t)row * N + col + nt * 16] = acc[nt][r] + bb;
        }
    }
}

// ---------------------------------------------------------------------------
// Deformable sampling. One block per query; 8 heads x 32 lanes.
// Phase 1: lane = point. Location + joint softmax + full bilinear setup
//          (4 clamped float4-unit indices, 4 mask*attn weights) -> LDS.
// Phase 2: lane = (point-sub pt4 = lane>>3, float4-channel c4 = lane&7).
//          8 iters x 4 corner dwordx4 gathers + 16 fmac; butterfly over pt4.
// Epilogue: pt4==0 lanes write hi/lo bf16 planes (A operand of out-GEMM).
// ---------------------------------------------------------------------------
__global__ __launch_bounds__(256) void sample_kernel(
    const float* __restrict__ value,   // (8160, 8, 32) fp32
    const float* __restrict__ proj,    // (8160, 768)
    const float* __restrict__ refp,    // (8160, 4, 2)
    const float* __restrict__ toff,    // (8160, 4, 2, 2)
    unsigned short* __restrict__ attn_hi,  // (8192, 256) bf16 plane
    unsigned short* __restrict__ attn_lo)
{
    const int q = blockIdx.x;
    const int head = threadIdx.x >> 5;
    const int lane = threadIdx.x & 31;
    __shared__ int4   s_idx[8][32];
    __shared__ float4 s_w[8][32];

    const float* p = proj + (size_t)q * 768;

    // ---- phase 1 ----
    {
        const int i = lane;
        float logit, ox, oy, rx, ry;
        int l;
        if (i < 16) {
            l = i >> 2; int pt2 = i & 3;
            logit = p[256 + head * 16 + i];
            ox = p[head * 32 + l * 8 + pt2 * 2 + 0];
            oy = p[head * 32 + l * 8 + pt2 * 2 + 1];
            rx = refp[q * 8 + l * 2 + 0];
            ry = refp[q * 8 + l * 2 + 1];
        } else {
            int j = i - 16; l = j >> 2;
            int tp = j & 3, tw = tp >> 1, nt = tp & 1;
            logit = p[640 + head * 16 + j];
            ox = p[384 + head * 32 + l * 8 + tw * 4 + nt * 2 + 0];
            oy = p[384 + head * 32 + l * 8 + tw * 4 + nt * 2 + 1];
            rx = refp[q * 8 + l * 2 + 0] + toff[q * 16 + l * 4 + tw * 2 + 0];
            ry = refp[q * 8 + l * 2 + 1] + toff[q * 16 + l * 4 + tw * 2 + 1];
        }
        const int Wl = 48 >> l;
        const int Hgl = 128 >> l;
        const int st = 8192 - (8192 >> (2 * l));
        const float fW = (float)Wl, fHg = (float)Hgl;
        float x = (rx + ox / fW) * fW - 0.5f;
        float y = (ry + oy / fHg) * fHg - 0.5f;

        float mx = logit;
        #pragma unroll
        for (int off = 16; off > 0; off >>= 1)
            mx = fmaxf(mx, __shfl_xor(mx, off, 32));
        float e = expf(logit - mx);
        float s = e;
        #pragma unroll
        for (int off = 16; off > 0; off >>= 1)
            s += __shfl_xor(s, off, 32);
        float w = e / s;

        float fx = floorf(x), fy = floorf(y);
        float wx = x - fx, wy = y - fy;
        int x0 = (int)fx, y0 = (int)fy;
        int x1 = x0 + 1, y1 = y0 + 1;
        float m00 = ((unsigned)x0 < (unsigned)Wl && (unsigned)y0 < (unsigned)Hgl) ? 1.f : 0.f;
        float m10 = ((unsigned)x1 < (unsigned)Wl && (unsigned)y0 < (unsigned)Hgl) ? 1.f : 0.f;
        float m01 = ((unsigned)x0 < (unsigned)Wl && (unsigned)y1 < (unsigned)Hgl) ? 1.f : 0.f;
        float m11 = ((unsigned)x1 < (unsigned)Wl && (unsigned)y1 < (unsigned)Hgl) ? 1.f : 0.f;
        int cx0 = min(max(x0, 0), Wl - 1), cx1 = min(max(x1, 0), Wl - 1);
        int cy0 = min(max(y0, 0), Hgl - 1), cy1 = min(max(y1, 0), Hgl - 1);
        int4 ii;   // indices in float4 units (row stride 64 float4s)
        ii.x = (st + cy0 * Wl + cx0) * 64;
        ii.y = (st + cy0 * Wl + cx1) * 64;
        ii.z = (st + cy1 * Wl + cx0) * 64;
        ii.w = (st + cy1 * Wl + cx1) * 64;
        float sx0 = 1.f - wx, sy0 = 1.f - wy;
        float4 ww;
        ww.x = w * sx0 * sy0 * m00;
        ww.y = w * wx  * sy0 * m10;
        ww.z = w * sx0 * wy  * m01;
        ww.w = w * wx  * wy  * m11;
        s_idx[head][lane] = ii;
        s_w[head][lane] = ww;
    }
    __syncthreads();

    // ---- phase 2: float4 gather, 4 points in flight per 32-lane group ----
    const int pt4 = lane >> 3;    // 0..3
    const int c4  = lane & 7;     // float4 channel group
    const float4* vb = (const float4*)value + head * 8 + c4;
    float4 acc = make_float4(0.f, 0.f, 0.f, 0.f);
    #pragma unroll 4
    for (int i = 0; i < 8; i++) {
        int pidx = (i << 2) | pt4;
        int4 ii = s_idx[head][pidx];
        float4 ww = s_w[head][pidx];
        float4 v0 = vb[ii.x], v1 = vb[ii.y], v2 = vb[ii.z], v3 = vb[ii.w];
        acc.x = fmaf(ww.x, v0.x, acc.x); acc.y = fmaf(ww.x, v0.y, acc.y);
        acc.z = fmaf(ww.x, v0.z, acc.z); acc.w = fmaf(ww.x, v0.w, acc.w);
        acc.x = fmaf(ww.y, v1.x, acc.x); acc.y = fmaf(ww.y, v1.y, acc.y);
        acc.z = fmaf(ww.y, v1.z, acc.z); acc.w = fmaf(ww.y, v1.w, acc.w);
        acc.x = fmaf(ww.z, v2.x, acc.x); acc.y = fmaf(ww.z, v2.y, acc.y);
        acc.z = fmaf(ww.z, v2.z, acc.z); acc.w = fmaf(ww.z, v2.w, acc.w);
        acc.x = fmaf(ww.w, v3.x, acc.x); acc.y = fmaf(ww.w, v3.y, acc.y);
        acc.z = fmaf(ww.w, v3.z, acc.z); acc.w = fmaf(ww.w, v3.w, acc.w);
    }
    // butterfly over the 4 pt4 groups (lanes xor 8, 16 within 32-lane group)
    #pragma unroll
    for (int off = 8; off <= 16; off <<= 1) {
        acc.x += __shfl_xor(acc.x, off, 32);
        acc.y += __shfl_xor(acc.y, off, 32);
        acc.z += __shfl_xor(acc.z, off, 32);
        acc.w += __shfl_xor(acc.w, off, 32);
    }
    if (pt4 == 0) {
        unsigned short h0, l0, h1, l1, h2, l2, h3, l3;
        split_bf16(acc.x, &h0, &l0); split_bf16(acc.y, &h1, &l1);
        split_bf16(acc.z, &h2, &l2); split_bf16(acc.w, &h3, &l3);
        uint2 hv, lv;
        hv.x = (unsigned)h0 | ((unsigned)h1 << 16);
        hv.y = (unsigned)h2 | ((unsigned)h3 << 16);
        lv.x = (unsigned)l0 | ((unsigned)l1 << 16);
        lv.y = (unsigned)l2 | ((unsigned)l3 << 16);
        size_t o = (size_t)q * 256 + head * 32 + c4 * 4;
        *(uint2*)(attn_hi + o) = hv;
        *(uint2*)(attn_lo + o) = lv;
    }
}

// ---------------------------------------------------------------------------
extern "C" void kernel_launch(void* const* d_in, const int* in_sizes, int n_in,
                              void* d_out, int out_size, void* d_ws, size_t ws_size,
                              hipStream_t stream)
{
    const float* query = (const float*)d_in[0];
    const float* refp  = (const float*)d_in[1];
    const float* toff  = (const float*)d_in[2];
    const float* inpf  = (const float*)d_in[3];
    const float* Wv  = (const float*)d_in[6];
    const float* bv  = (const float*)d_in[7];
    const float* Ws_ = (const float*)d_in[8];
    const float* bs_ = (const float*)d_in[9];
    const float* Wa  = (const float*)d_in[10];
    const float* ba  = (const float*)d_in[11];
    const float* Wts = (const float*)d_in[12];
    const float* bts = (const float*)d_in[13];
    const float* Wta = (const float*)d_in[14];
    const float* bta = (const float*)d_in[15];
    const float* Wo  = (const float*)d_in[16];
    const float* bo  = (const float*)d_in[17];
    float* out = (float*)d_out;

    // workspace layout (~51.5 MB)
    float* ws    = (float*)d_ws;
    float* value = ws;                              // 8160*256 f32
    float* proj  = value + (size_t)LEN * 256;       // 8160*768 f32
    float* bcat  = proj + (size_t)LEN * 768;        // 768 f32
    unsigned short* Whi = (unsigned short*)(bcat + 768);   // 1280*256 bf16
    unsigned short* Wlo = Whi + 1280 * 256;
    unsigned short* Ahi = Wlo + 1280 * 256;         // 8192*256: inpf planes, later attn planes
    unsigned short* Alo = Ahi + 8192 * 256;
    unsigned short* Qhi = Alo + 8192 * 256;         // 8192*256: query planes
    unsigned short* Qlo = Qhi + 8192 * 256;

    dim3 blk(256);
    prep_kernel<<<17603, blk, 0, stream>>>(inpf, query, Ws_, bs_, Wa, ba,
                                           Wts, bts, Wta, bta, Wv, Wo,
                                           Ahi, Alo, Qhi, Qlo, Whi, Wlo, bcat);
    // value = inpf @ Wv + bv  (bx 0..3)  ||  proj = query @ Bcat + bcat (bx 4..15)
    gemm_mfma_dual<<<dim3(16, 128), blk, 0, stream>>>(
        Ahi, Alo, Whi, Wlo, bv, value, 256, 4,
        Qhi, Qlo, Whi + 256 * 256, Wlo + 256 * 256, bcat, proj, 768);
    // deformable attention core -> attn planes (reuse Ahi/Alo: inpf planes dead)
    sample_kernel<<<LEN, blk, 0, stream>>>(value, proj, refp, toff, Ahi, Alo);
    // out = attn @ Wo + bo
    gemm_mfma_dual<<<dim3(4, 128), blk, 0, stream>>>(
        Ahi, Alo, Whi + 1024 * 256, Wlo + 1024 * 256, bo, out, 256, 4,
        Ahi, Alo, Whi + 1024 * 256, Wlo + 1024 * 256, bo, out, 256);
}

// Round 5
// 184.941 us; speedup vs baseline: 1.6178x; 1.0166x over previous
//
#include <hip/hip_runtime.h>

// Problem constants (hard-coded from reference: SHAPES fixed at trace time)
// Level l: W=48>>l, Hgrid=128>>l, start = 8192 - (8192 >> (2*l)); LEN=8160.

#define LEN 8160
#define NCONV8 (2 * LEN * 256 / 8)   // 522,240  (8-elem conv units)
#define NPACK8 (1280 * 256 / 8)      // 40,960   (8-elem pack units)

typedef __attribute__((ext_vector_type(8))) short bf16x8;
typedef __attribute__((ext_vector_type(8))) unsigned short u16x8;
typedef __attribute__((ext_vector_type(4))) float f32x4;

// Round-to-nearest-even fp32 -> bf16 (single)
__device__ __forceinline__ unsigned short rne_bf16(float v)
{
    unsigned u = __float_as_uint(v);
    return (unsigned short)((u + 0x7FFFu + ((u >> 16) & 1u)) >> 16);
}

// Round-to-nearest-even split of fp32 into hi+lo bf16 (bf16x3 GEMM trick).
__device__ __forceinline__ void split_bf16(float v, unsigned short* hi, unsigned short* lo)
{
    unsigned u = __float_as_uint(v);
    unsigned r = (u + 0x7FFFu + ((u >> 16) & 1u)) & 0xFFFF0000u;
    float hif = __uint_as_float(r);
    float lof = v - hif;
    unsigned ul = __float_as_uint(lof);
    unsigned rl = (ul + 0x7FFFu + ((ul >> 16) & 1u)) >> 16;
    *hi = (unsigned short)(r >> 16);
    *lo = (unsigned short)rl;
}

__device__ __forceinline__ float bf2f(unsigned short s)
{
    return __uint_as_float(((unsigned)s) << 16);
}

// ---------------------------------------------------------------------------
// prep: convA (split inpf+query into hi/lo planes, 8 elems/thread) + pack
// (weights transposed into hi/lo planes, 8 k's/thread) + concat bias.
// W row space: [0,256)=WvT [256,1024)=BcatT(Ws|Wa|Wts|Wta) [1024,1280)=WoT.
// ---------------------------------------------------------------------------
__global__ __launch_bounds__(256) void prep_kernel(
    const float* __restrict__ inpf, const float* __restrict__ query,
    const float* __restrict__ Ws, const float* __restrict__ bs,
    const float* __restrict__ Wa, const float* __restrict__ ba,
    const float* __restrict__ Wts, const float* __restrict__ bts,
    const float* __restrict__ Wta, const float* __restrict__ bta,
    const float* __restrict__ Wv, const float* __restrict__ Wo,
    unsigned short* __restrict__ Ahi, unsigned short* __restrict__ Alo,
    unsigned short* __restrict__ Qhi, unsigned short* __restrict__ Qlo,
    unsigned short* __restrict__ Whi, unsigned short* __restrict__ Wlo,
    float* __restrict__ bcat)
{
    int idx = blockIdx.x * 256 + threadIdx.x;
    if (idx < NCONV8) {
        int which = (idx >= NCONV8 / 2) ? 1 : 0;
        int off = (idx - which * (NCONV8 / 2)) * 8;
        const float* src = which ? query : inpf;
        float4 a = *(const float4*)(src + off);
        float4 b = *(const float4*)(src + off + 4);
        unsigned short h[8], l[8];
        split_bf16(a.x, &h[0], &l[0]); split_bf16(a.y, &h[1], &l[1]);
        split_bf16(a.z, &h[2], &l[2]); split_bf16(a.w, &h[3], &l[3]);
        split_bf16(b.x, &h[4], &l[4]); split_bf16(b.y, &h[5], &l[5]);
        split_bf16(b.z, &h[6], &l[6]); split_bf16(b.w, &h[7], &l[7]);
        uint4 hv, lv;
        hv.x = h[0] | ((unsigned)h[1] << 16); hv.y = h[2] | ((unsigned)h[3] << 16);
        hv.z = h[4] | ((unsigned)h[5] << 16); hv.w = h[6] | ((unsigned)h[7] << 16);
        lv.x = l[0] | ((unsigned)l[1] << 16); lv.y = l[2] | ((unsigned)l[3] << 16);
        lv.z = l[4] | ((unsigned)l[5] << 16); lv.w = l[6] | ((unsigned)l[7] << 16);
        if (which) { *(uint4*)(Qhi + off) = hv; *(uint4*)(Qlo + off) = lv; }
        else       { *(uint4*)(Ahi + off) = hv; *(uint4*)(Alo + off) = lv; }
    } else if (idx < NCONV8 + NPACK8) {
        int j8 = idx - NCONV8;
        int n = j8 >> 5;
        int k0 = (j8 & 31) << 3;
        unsigned short h[8], l[8];
        #pragma unroll
        for (int t = 0; t < 8; t++) {
            int k = k0 + t;
            float v;
            if (n < 256) v = Wv[k * 256 + n];
            else if (n < 1024) {
                int j = n - 256;
                if (j < 256)      v = Ws [k * 256 + j];
                else if (j < 384) v = Wa [k * 128 + (j - 256)];
                else if (j < 640) v = Wts[k * 256 + (j - 384)];
                else              v = Wta[k * 128 + (j - 640)];
            } else v = Wo[k * 256 + (n - 1024)];
            split_bf16(v, &h[t], &l[t]);
        }
        uint4 hv, lv;
        hv.x = h[0] | ((unsigned)h[1] << 16); hv.y = h[2] | ((unsigned)h[3] << 16);
        hv.z = h[4] | ((unsigned)h[5] << 16); hv.w = h[6] | ((unsigned)h[7] << 16);
        lv.x = l[0] | ((unsigned)l[1] << 16); lv.y = l[2] | ((unsigned)l[3] << 16);
        lv.z = l[4] | ((unsigned)l[5] << 16); lv.w = l[6] | ((unsigned)l[7] << 16);
        *(uint4*)(Whi + n * 256 + k0) = hv;
        *(uint4*)(Wlo + n * 256 + k0) = lv;
    } else if (idx < NCONV8 + NPACK8 + 768) {
        int j = idx - (NCONV8 + NPACK8);
        float v;
        if (j < 256)      v = bs[j];
        else if (j < 384) v = ba[j - 256];
        else if (j < 640) v = bts[j - 384];
        else              v = bta[j - 640];
        bcat[j] = v;
    }
}

// ---------------------------------------------------------------------------
// bf16x3 MFMA GEMM, dual problem-set. Tile 256(M)x64(N), K=256 FULLY resident
// in LDS in fragment order (conflict-free 16B/lane reads), ONE barrier.
// 512 threads = 8 waves; wave owns 32 rows (2 x 16-row subtiles).
// mode: 0 = f32 store, 1 = bf16 (RNE) store.
// ---------------------------------------------------------------------------
__global__ __launch_bounds__(512) void gemm_mfma_dual(
    const unsigned short* __restrict__ A0hi, const unsigned short* __restrict__ A0lo,
    const unsigned short* __restrict__ B0hi, const unsigned short* __restrict__ B0lo,
    const float* __restrict__ bias0, void* __restrict__ C0, int N0, int mode0, int nbx0,
    const unsigned short* __restrict__ A1hi, const unsigned short* __restrict__ A1lo,
    const unsigned short* __restrict__ B1hi, const unsigned short* __restrict__ B1lo,
    const float* __restrict__ bias1, void* __restrict__ C1, int N1, int mode1)
{
    // frag-order LDS: [plane][kt][nt][lane][8 bf16] = 64 KB
    __shared__ unsigned short Bf[2 * 8 * 4 * 64 * 8];
    const int tid = threadIdx.x;
    const int wave = tid >> 6, lane = tid & 63;
    int bx = blockIdx.x;
    const int by = blockIdx.y;

    const unsigned short *Ahi, *Alo, *Bhi, *Blo;
    const float* bias; void* C; int N, mode;
    if (bx < nbx0) {
        Ahi = A0hi; Alo = A0lo; Bhi = B0hi; Blo = B0lo;
        bias = bias0; C = C0; N = N0; mode = mode0;
    } else {
        bx -= nbx0;
        Ahi = A1hi; Alo = A1lo; Bhi = B1hi; Blo = B1lo;
        bias = bias1; C = C1; N = N1; mode = mode1;
    }

    // ---- stage full B tile (both planes) into frag-order LDS ----
    #pragma unroll
    for (int t = 0; t < 8; t++) {
        int f = t * 512 + tid;
        int ln = f & 63, nt = (f >> 6) & 3, kt = (f >> 8) & 7, pl = f >> 11;
        const unsigned short* src = (pl ? Blo : Bhi)
            + (size_t)(bx * 64 + nt * 16 + (ln & 15)) * 256 + kt * 32 + (ln >> 4) * 8;
        *(uint4*)(&Bf[(size_t)f * 8]) = *(const uint4*)src;
    }
    __syncthreads();

    const int lm = lane & 15;     // m within 16-tile / C column
    const int kq = lane >> 4;     // k-quad (0..3)
    const int m0 = by * 256 + wave * 32 + lm;
    const unsigned short* aH0 = Ahi + (size_t)m0 * 256 + kq * 8;
    const unsigned short* aL0 = Alo + (size_t)m0 * 256 + kq * 8;

    f32x4 acc[2][4] = {};
    #pragma unroll
    for (int kt = 0; kt < 8; kt++) {
        bf16x8 ah0 = *(const bf16x8*)(aH0 + kt * 32);
        bf16x8 al0 = *(const bf16x8*)(aL0 + kt * 32);
        bf16x8 ah1 = *(const bf16x8*)(aH0 + 16 * 256 + kt * 32);
        bf16x8 al1 = *(const bf16x8*)(aL0 + 16 * 256 + kt * 32);
        #pragma unroll
        for (int nt = 0; nt < 4; nt++) {
            const int fb = (kt * 4 + nt) * 64 + lane;
            bf16x8 bh = *(const bf16x8*)(&Bf[(size_t)fb * 8]);
            bf16x8 bl = *(const bf16x8*)(&Bf[(size_t)(fb + 2048) * 8]);
            acc[0][nt] = __builtin_amdgcn_mfma_f32_16x16x32_bf16(ah0, bh, acc[0][nt], 0, 0, 0);
            acc[0][nt] = __builtin_amdgcn_mfma_f32_16x16x32_bf16(ah0, bl, acc[0][nt], 0, 0, 0);
            acc[0][nt] = __builtin_amdgcn_mfma_f32_16x16x32_bf16(al0, bh, acc[0][nt], 0, 0, 0);
            acc[1][nt] = __builtin_amdgcn_mfma_f32_16x16x32_bf16(ah1, bh, acc[1][nt], 0, 0, 0);
            acc[1][nt] = __builtin_amdgcn_mfma_f32_16x16x32_bf16(ah1, bl, acc[1][nt], 0, 0, 0);
            acc[1][nt] = __builtin_amdgcn_mfma_f32_16x16x32_bf16(al1, bh, acc[1][nt], 0, 0, 0);
        }
    }

    // C/D layout (verified m89/m91): col = lane&15, row = (lane>>4)*4 + reg
    const int col = bx * 64 + lm;
    #pragma unroll
    for (int sub = 0; sub < 2; sub++) {
        const int row0 = by * 256 + wave * 32 + sub * 16 + kq * 4;
        #pragma unroll
        for (int nt = 0; nt < 4; nt++) {
            float bb = bias[col + nt * 16];
            #pragma unroll
            for (int r = 0; r < 4; r++) {
                int row = row0 + r;
                if (row < LEN) {
                    float v = acc[sub][nt][r] + bb;
                    if (mode) ((unsigned short*)C)[(size_t)row * N + col + nt * 16] = rne_bf16(v);
                    else      ((float*)C)[(size_t)row * N + col + nt * 16] = v;
                }
            }
        }
    }
}

// ---------------------------------------------------------------------------
// Deformable sampling. One block per query; 8 heads x 32 lanes.
// Phase 1: lane = point. Location + joint softmax + full bilinear setup
//          (4 clamped BYTE offsets, 4 mask*attn weights) -> LDS.
// Phase 2: 8 points in flight: pt8 = lane>>2, cg = lane&3 (8 bf16 channels,
//          16B loads). 4 iters x 4 corner gathers; butterfly over pt8.
// Epilogue: pt8==0 lanes write hi/lo bf16 planes (A operand of out-GEMM).
// ---------------------------------------------------------------------------
__global__ __launch_bounds__(256) void sample_kernel(
    const unsigned short* __restrict__ value,  // (8160, 8, 32) bf16
    const float* __restrict__ proj,    // (8160, 768)
    const float* __restrict__ refp,    // (8160, 4, 2)
    const float* __restrict__ toff,    // (8160, 4, 2, 2)
    unsigned short* __restrict__ attn_hi,  // (8192, 256) bf16 plane
    unsigned short* __restrict__ attn_lo)
{
    const int q = blockIdx.x;
    const int head = threadIdx.x >> 5;
    const int lane = threadIdx.x & 31;
    __shared__ int4   s_idx[8][32];
    __shared__ float4 s_w[8][32];

    const float* p = proj + (size_t)q * 768;

    // ---- phase 1 ----
    {
        const int i = lane;
        float logit, ox, oy, rx, ry;
        int l;
        if (i < 16) {
            l = i >> 2; int pt2 = i & 3;
            logit = p[256 + head * 16 + i];
            ox = p[head * 32 + l * 8 + pt2 * 2 + 0];
            oy = p[head * 32 + l * 8 + pt2 * 2 + 1];
            rx = refp[q * 8 + l * 2 + 0];
            ry = refp[q * 8 + l * 2 + 1];
        } else {
            int j = i - 16; l = j >> 2;
            int tp = j & 3, tw = tp >> 1, nt = tp & 1;
            logit = p[640 + head * 16 + j];
            ox = p[384 + head * 32 + l * 8 + tw * 4 + nt * 2 + 0];
            oy = p[384 + head * 32 + l * 8 + tw * 4 + nt * 2 + 1];
            rx = refp[q * 8 + l * 2 + 0] + toff[q * 16 + l * 4 + tw * 2 + 0];
            ry = refp[q * 8 + l * 2 + 1] + toff[q * 16 + l * 4 + tw * 2 + 1];
        }
        const int Wl = 48 >> l;
        const int Hgl = 128 >> l;
        const int st = 8192 - (8192 >> (2 * l));
        const float fW = (float)Wl, fHg = (float)Hgl;
        float x = (rx + ox / fW) * fW - 0.5f;
        float y = (ry + oy / fHg) * fHg - 0.5f;

        float mx = logit;
        #pragma unroll
        for (int off = 16; off > 0; off >>= 1)
            mx = fmaxf(mx, __shfl_xor(mx, off, 32));
        float e = expf(logit - mx);
        float s = e;
        #pragma unroll
        for (int off = 16; off > 0; off >>= 1)
            s += __shfl_xor(s, off, 32);
        float w = e / s;

        float fx = floorf(x), fy = floorf(y);
        float wx = x - fx, wy = y - fy;
        int x0 = (int)fx, y0 = (int)fy;
        int x1 = x0 + 1, y1 = y0 + 1;
        float m00 = ((unsigned)x0 < (unsigned)Wl && (unsigned)y0 < (unsigned)Hgl) ? 1.f : 0.f;
        float m10 = ((unsigned)x1 < (unsigned)Wl && (unsigned)y0 < (unsigned)Hgl) ? 1.f : 0.f;
        float m01 = ((unsigned)x0 < (unsigned)Wl && (unsigned)y1 < (unsigned)Hgl) ? 1.f : 0.f;
        float m11 = ((unsigned)x1 < (unsigned)Wl && (unsigned)y1 < (unsigned)Hgl) ? 1.f : 0.f;
        int cx0 = min(max(x0, 0), Wl - 1), cx1 = min(max(x1, 0), Wl - 1);
        int cy0 = min(max(y0, 0), Hgl - 1), cy1 = min(max(y1, 0), Hgl - 1);
        int4 ii;   // BYTE offsets (512 B per position: 8 heads x 32 ch x 2B)
        ii.x = (st + cy0 * Wl + cx0) * 512;
        ii.y = (st + cy0 * Wl + cx1) * 512;
        ii.z = (st + cy1 * Wl + cx0) * 512;
        ii.w = (st + cy1 * Wl + cx1) * 512;
        float sx0 = 1.f - wx, sy0 = 1.f - wy;
        float4 ww;
        ww.x = w * sx0 * sy0 * m00;
        ww.y = w * wx  * sy0 * m10;
        ww.z = w * sx0 * wy  * m01;
        ww.w = w * wx  * wy  * m11;
        s_idx[head][lane] = ii;
        s_w[head][lane] = ww;
    }
    __syncthreads();

    // ---- phase 2: bf16 gather, 8 points in flight per 32-lane group ----
    const int pt8 = lane >> 2;    // 0..7
    const int cg  = lane & 3;     // 8-channel group
    const char* vbase = (const char*)value + head * 64 + cg * 16;
    float acc[8] = {0.f, 0.f, 0.f, 0.f, 0.f, 0.f, 0.f, 0.f};
    #pragma unroll
    for (int i = 0; i < 4; i++) {
        int pidx = (i << 3) | pt8;
        int4 ii = s_idx[head][pidx];
        float4 ww = s_w[head][pidx];
        u16x8 v0 = *(const u16x8*)(vbase + ii.x);
        u16x8 v1 = *(const u16x8*)(vbase + ii.y);
        u16x8 v2 = *(const u16x8*)(vbase + ii.z);
        u16x8 v3 = *(const u16x8*)(vbase + ii.w);
        #pragma unroll
        for (int j = 0; j < 8; j++) {
            acc[j] = fmaf(ww.x, bf2f(v0[j]), acc[j]);
            acc[j] = fmaf(ww.y, bf2f(v1[j]), acc[j]);
            acc[j] = fmaf(ww.z, bf2f(v2[j]), acc[j]);
            acc[j] = fmaf(ww.w, bf2f(v3[j]), acc[j]);
        }
    }
    // butterfly over the 8 pt8 groups (lane bits 2..4)
    #pragma unroll
    for (int off = 4; off <= 16; off <<= 1)
        #pragma unroll
        for (int j = 0; j < 8; j++)
            acc[j] += __shfl_xor(acc[j], off, 32);

    if (pt8 == 0) {
        unsigned short h[8], l[8];
        #pragma unroll
        for (int j = 0; j < 8; j++) split_bf16(acc[j], &h[j], &l[j]);
        uint4 hv, lv;
        hv.x = h[0] | ((unsigned)h[1] << 16); hv.y = h[2] | ((unsigned)h[3] << 16);
        hv.z = h[4] | ((unsigned)h[5] << 16); hv.w = h[6] | ((unsigned)h[7] << 16);
        lv.x = l[0] | ((unsigned)l[1] << 16); lv.y = l[2] | ((unsigned)l[3] << 16);
        lv.z = l[4] | ((unsigned)l[5] << 16); lv.w = l[6] | ((unsigned)l[7] << 16);
        size_t o = (size_t)q * 256 + head * 32 + cg * 8;
        *(uint4*)(attn_hi + o) = hv;
        *(uint4*)(attn_lo + o) = lv;
    }
}

// ---------------------------------------------------------------------------
extern "C" void kernel_launch(void* const* d_in, const int* in_sizes, int n_in,
                              void* d_out, int out_size, void* d_ws, size_t ws_size,
                              hipStream_t stream)
{
    const float* query = (const float*)d_in[0];
    const float* refp  = (const float*)d_in[1];
    const float* toff  = (const float*)d_in[2];
    const float* inpf  = (const float*)d_in[3];
    const float* Wv  = (const float*)d_in[6];
    const float* bv  = (const float*)d_in[7];
    const float* Ws_ = (const float*)d_in[8];
    const float* bs_ = (const float*)d_in[9];
    const float* Wa  = (const float*)d_in[10];
    const float* ba  = (const float*)d_in[11];
    const float* Wts = (const float*)d_in[12];
    const float* bts = (const float*)d_in[13];
    const float* Wta = (const float*)d_in[14];
    const float* bta = (const float*)d_in[15];
    const float* Wo  = (const float*)d_in[16];
    const float* bo  = (const float*)d_in[17];
    float* out = (float*)d_out;

    // workspace layout (~49 MB)
    unsigned short* value_bf = (unsigned short*)d_ws;          // 8160*256 bf16
    float* proj = (float*)(value_bf + (size_t)LEN * 256);      // 8160*768 f32
    float* bcat = proj + (size_t)LEN * 768;                    // 768 f32
    unsigned short* Whi = (unsigned short*)(bcat + 768);       // 1280*256
    unsigned short* Wlo = Whi + 1280 * 256;
    unsigned short* Ahi = Wlo + 1280 * 256;                    // 8192*256 (inpf, later attn)
    unsigned short* Alo = Ahi + (size_t)8192 * 256;
    unsigned short* Qhi = Alo + (size_t)8192 * 256;            // 8192*256 (query)
    unsigned short* Qlo = Qhi + (size_t)8192 * 256;

    prep_kernel<<<2203, 256, 0, stream>>>(inpf, query, Ws_, bs_, Wa, ba,
                                          Wts, bts, Wta, bta, Wv, Wo,
                                          Ahi, Alo, Qhi, Qlo, Whi, Wlo, bcat);
    // value(bf16) = inpf @ Wv + bv (bx 0..3) || proj(f32) = query @ Bcat + bcat (bx 4..15)
    gemm_mfma_dual<<<dim3(16, 32), 512, 0, stream>>>(
        Ahi, Alo, Whi, Wlo, bv, value_bf, 256, 1, 4,
        Qhi, Qlo, Whi + 256 * 256, Wlo + 256 * 256, bcat, proj, 768, 0);
    // deformable attention core -> attn planes (reuse Ahi/Alo)
    sample_kernel<<<LEN, 256, 0, stream>>>(value_bf, proj, refp, toff, Ahi, Alo);
    // out(f32) = attn @ Wo + bo
    gemm_mfma_dual<<<dim3(4, 32), 512, 0, stream>>>(
        Ahi, Alo, Whi + 1024 * 256, Wlo + 1024 * 256, bo, out, 256, 0, 4,
        Ahi, Alo, Whi + 1024 * 256, Wlo + 1024 * 256, bo, out, 256, 0);
}